// Round 2
// baseline (159.937 us; speedup 1.0000x reference)
//
#include <hip/hip_runtime.h>
#include <hip/hip_cooperative_groups.h>

namespace cg = cooperative_groups;

#define N_CODECS 1024
#define EPS 1e-8f
#define BLOCKS 256          // 1 block per CU, co-resident (cooperative)
#define THREADS 1024        // 16 waves/CU — same 262144 total threads as the
                            // proven round-0 hist schedule

// ---------------------------------------------------------------------------
// Single cooperative kernel, 3 phases separated by grid.sync():
//   P1: per-block LDS histogram (round-0 hot loop: cached int4 loads, 2-deep
//       MLP, LDS atomics) -> plain coalesced store of the 4 KB block partial.
//       Partials total 1 MB (vs round-0's 4 MB).
//   P2: grid-parallel column reduce: block b owns bins [4b, 4b+4); each of
//       its 1024 threads reads ONE partial dword (L2-resident), wave shuffle
//       reduce, 4 terms p*log(p+eps) -> one float per block (plain store).
//   P3: block 0 folds 256 block-terms -> out = exp(-sum).
// No global atomics, no counters in poisoned memory, no memset dispatch.
// grid.sync() provides the cross-XCD release/acquire (Guideline 16).
// NOTE: plain cached loads for the input — NT loads bypass L3 and regressed
// +6us in an earlier round; input is L3-resident after the harness restore.
// ---------------------------------------------------------------------------
__global__ void __launch_bounds__(THREADS) fused_hist_perplexity(
        const int* __restrict__ idx,
        unsigned int* __restrict__ gpart,   // [BLOCKS][N_CODECS]  (1 MB)
        float* __restrict__ bterm,          // [BLOCKS]            (1 KB)
        float* __restrict__ out,
        int n4, float invN) {
    cg::grid_group grid = cg::this_grid();

    __shared__ unsigned int lcounts[N_CODECS];
    __shared__ float lred[16];

    // THREADS == N_CODECS: one bin per thread
    lcounts[threadIdx.x] = 0u;
    __syncthreads();

    // ---- P1: histogram (identical memory schedule to round 0) ----
    const int4* __restrict__ idx4 = (const int4*)idx;
    const int S = gridDim.x * THREADS;               // 262144
    for (int i = blockIdx.x * THREADS + threadIdx.x; i < n4; i += 2 * S) {
        int4 a = idx4[i];
        int j = i + S;
        bool has_b = (j < n4);
        int4 b = has_b ? idx4[j] : make_int4(0, 0, 0, 0);

        atomicAdd(&lcounts[a.x], 1u);                // LDS atomics only
        atomicAdd(&lcounts[a.y], 1u);
        atomicAdd(&lcounts[a.z], 1u);
        atomicAdd(&lcounts[a.w], 1u);
        if (has_b) {
            atomicAdd(&lcounts[b.x], 1u);
            atomicAdd(&lcounts[b.y], 1u);
            atomicAdd(&lcounts[b.z], 1u);
            atomicAdd(&lcounts[b.w], 1u);
        }
    }
    __syncthreads();

    // contention-free merge: coalesced 4 KB store of this block's partial
    gpart[(size_t)blockIdx.x * N_CODECS + threadIdx.x] = lcounts[threadIdx.x];

    grid.sync();

    // ---- P2: block b reduces bins [4b, 4b+4) over 256 partials ----
    int t = threadIdx.x;
    int bin = 4 * blockIdx.x + (t >> 8);   // 4 groups of 256 threads
    int row = t & 255;                     // one partial row per thread
    unsigned int v = gpart[(size_t)row * N_CODECS + bin];

    #pragma unroll
    for (int off = 32; off > 0; off >>= 1) v += __shfl_down(v, off, 64);

    int wave = t >> 6, lane = t & 63;
    if (lane == 0) lred[wave] = (float)v;  // counts < 2^24: exact in float
    __syncthreads();

    if (t < 4) {
        // bin group t: wave partials lred[4t .. 4t+3]
        float cnt = lred[4 * t] + lred[4 * t + 1] + lred[4 * t + 2] + lred[4 * t + 3];
        float p = cnt * invN;
        float term = p * logf(p + EPS);
        term += __shfl_down(term, 2, 64);
        term += __shfl_down(term, 1, 64);
        if (t == 0) bterm[blockIdx.x] = term;   // plain store
    }

    grid.sync();

    // ---- P3: block 0 folds the 256 block terms ----
    if (blockIdx.x == 0) {
        float s = (t < BLOCKS) ? bterm[t] : 0.0f;
        #pragma unroll
        for (int off = 32; off > 0; off >>= 1) s += __shfl_down(s, off, 64);
        __syncthreads();                       // lred reuse after P2
        if (lane == 0) lred[wave] = s;         // waves 4..15 contribute 0
        __syncthreads();
        if (t == 0) {
            float tot = 0.0f;
            #pragma unroll
            for (int w = 0; w < 16; ++w) tot += lred[w];
            out[0] = expf(-tot);
        }
    }
}

extern "C" void kernel_launch(void* const* d_in, const int* in_sizes, int n_in,
                              void* d_out, int out_size, void* d_ws, size_t ws_size,
                              hipStream_t stream) {
    const int* indices = (const int*)d_in[0];
    int n = in_sizes[0];             // 16 * 1048576 = 16,777,216 elements
    float* out = (float*)d_out;

    unsigned int* gpart = (unsigned int*)d_ws;                     // 1 MB
    float* bterm = (float*)(gpart + (size_t)BLOCKS * N_CODECS);    // 1 KB

    int n4 = n >> 2;
    float invN = 1.0f / (float)n;

    void* args[] = { (void*)&indices, (void*)&gpart, (void*)&bterm,
                     (void*)&out, (void*)&n4, (void*)&invN };
    hipLaunchCooperativeKernel((const void*)fused_hist_perplexity,
                               dim3(BLOCKS), dim3(THREADS), args, 0, stream);
}

// Round 3
// 96.356 us; speedup vs baseline: 1.6598x; 1.6598x over previous
//
#include <hip/hip_runtime.h>

#define N_CODECS 1024
#define EPS 1e-8f
#define HIST_BLOCKS 2048       // 8 blocks/CU -> 32 waves/CU (full occupancy)
#define CHUNKS 32              // 2048 partials reduced in 32 chunks of 64

// ---------------------------------------------------------------------------
// Kernel 1: per-block LDS histogram -> private partial in d_ws (NO global
// atomics). Round-2 post-mortem showed the old config (1024 blocks, 2-deep
// loads) was LATENCY-bound: VALUBusy ~2%, 28% of HBM BW. Fix: full occupancy
// (8 blocks/CU) + 8 upfront int4 loads per thread (8 KB in flight per wave,
// staged vmcnt consumption). Plain cached loads — NT loads bypass L3 and
// regressed +6us in an earlier round.
// ---------------------------------------------------------------------------
__global__ void __launch_bounds__(256) hist_partial_kernel(
        const int* __restrict__ idx,
        unsigned int* __restrict__ gpart,   // [HIST_BLOCKS][N_CODECS]
        int n4) {
    __shared__ unsigned int lcounts[N_CODECS];
    #pragma unroll
    for (int i = threadIdx.x; i < N_CODECS; i += 256) lcounts[i] = 0u;
    __syncthreads();

    const int4* __restrict__ idx4 = (const int4*)idx;
    const int S = gridDim.x * 256;          // 524288; n4 = 4194304 = 8*S
    for (int i = blockIdx.x * 256 + threadIdx.x; i < n4; i += 8 * S) {
        int4 v[8];
        bool h[8];
        // issue all 8 independent loads first (full unroll -> static indexing)
        #pragma unroll
        for (int k = 0; k < 8; ++k) {
            int j = i + k * S;
            h[k] = (j < n4);
            v[k] = h[k] ? idx4[j] : make_int4(0, 0, 0, 0);
        }
        // consume in order; compiler stages s_waitcnt vmcnt(7..0)
        #pragma unroll
        for (int k = 0; k < 8; ++k) {
            if (h[k]) {
                atomicAdd(&lcounts[v[k].x], 1u);   // LDS atomics only
                atomicAdd(&lcounts[v[k].y], 1u);
                atomicAdd(&lcounts[v[k].z], 1u);
                atomicAdd(&lcounts[v[k].w], 1u);
            }
        }
    }
    __syncthreads();

    // contention-free merge: plain coalesced stores to this block's slice
    unsigned int* __restrict__ mypart = gpart + (size_t)blockIdx.x * N_CODECS;
    #pragma unroll
    for (int i = 0; i < N_CODECS / 256; ++i) {
        int b = i * 256 + threadIdx.x;
        mypart[b] = lcounts[b];
    }
}

// ---------------------------------------------------------------------------
// Kernel 2: reduce 2048 partials -> 32 chunk partials (column sums).
// Grid: 128 blocks x 256 threads. Block (c,q): chunk c=blk>>2, quarter q=blk&3.
// Thread handles bin = q*256 + tid, sums 64 partials. Fully coalesced
// (a wave reads 64 consecutive bins of one row = 256 B segment).
// ---------------------------------------------------------------------------
__global__ void __launch_bounds__(256) reduce_kernel(
        const unsigned int* __restrict__ gpart,   // [HIST_BLOCKS][N_CODECS]
        unsigned int* __restrict__ p2) {          // [CHUNKS][N_CODECS]
    int c = blockIdx.x >> 2;
    int q = blockIdx.x & 3;
    int bin = q * 256 + threadIdx.x;

    const unsigned int* __restrict__ base = gpart + (size_t)(c * 64) * N_CODECS + bin;
    unsigned int s0 = 0, s1 = 0, s2 = 0, s3 = 0;
    #pragma unroll 4
    for (int k = 0; k < 64; k += 4) {
        s0 += base[(size_t)(k + 0) * N_CODECS];
        s1 += base[(size_t)(k + 1) * N_CODECS];
        s2 += base[(size_t)(k + 2) * N_CODECS];
        s3 += base[(size_t)(k + 3) * N_CODECS];
    }
    p2[c * N_CODECS + bin] = s0 + s1 + s2 + s3;
}

// ---------------------------------------------------------------------------
// Kernel 3: finalize. 1 block x 1024 threads: sum 32 chunk values per bin,
// p = count/N, term = p*log(p+eps), block reduce, out = exp(-sum).
// ---------------------------------------------------------------------------
__global__ void __launch_bounds__(1024) finalize_kernel(
        const unsigned int* __restrict__ p2,      // [CHUNKS][N_CODECS]
        float* __restrict__ out,
        float invN) {
    int t = threadIdx.x;
    unsigned int cnt = 0;
    #pragma unroll
    for (int c = 0; c < CHUNKS; ++c) cnt += p2[c * N_CODECS + t];

    float p = (float)cnt * invN;
    float term = p * logf(p + EPS);

    #pragma unroll
    for (int off = 32; off > 0; off >>= 1) term += __shfl_down(term, off, 64);

    __shared__ float wsum[16];
    int wave = t >> 6;
    int lane = t & 63;
    if (lane == 0) wsum[wave] = term;
    __syncthreads();

    if (wave == 0) {
        float s = (lane < 16) ? wsum[lane] : 0.0f;
        #pragma unroll
        for (int off = 8; off > 0; off >>= 1) s += __shfl_down(s, off, 64);
        if (lane == 0) out[0] = expf(-s);
    }
}

extern "C" void kernel_launch(void* const* d_in, const int* in_sizes, int n_in,
                              void* d_out, int out_size, void* d_ws, size_t ws_size,
                              hipStream_t stream) {
    const int* indices = (const int*)d_in[0];
    int n = in_sizes[0];             // 16 * 1048576 = 16,777,216
    float* out = (float*)d_out;

    unsigned int* gpart = (unsigned int*)d_ws;                       // 8 MB
    unsigned int* p2    = gpart + (size_t)HIST_BLOCKS * N_CODECS;    // 128 KB

    int n4 = n >> 2;

    hist_partial_kernel<<<HIST_BLOCKS, 256, 0, stream>>>(indices, gpart, n4);
    reduce_kernel<<<CHUNKS * 4, 256, 0, stream>>>(gpart, p2);
    finalize_kernel<<<1, 1024, 0, stream>>>(p2, out, 1.0f / (float)n);
}

// Round 4
// 94.909 us; speedup vs baseline: 1.6852x; 1.0152x over previous
//
#include <hip/hip_runtime.h>

#define N_CODECS 1024
#define EPS 1e-8f
#define HIST_BLOCKS 1024       // proven R0 config: 4 blocks/CU, 16 waves/CU
#define RED_BLOCKS 128
#define RED_THREADS 512
#define ROWS_PER_RED (HIST_BLOCKS / RED_BLOCKS)   // 8

// ---------------------------------------------------------------------------
// Kernel 1: per-block LDS histogram -> private partial in d_ws. BYTE-IDENTICAL
// hot loop to the measured-93.5us round-0 kernel (R3 proved more occupancy /
// deeper staging does NOT improve it; R2 proved less occupancy cripples it).
// Plain cached int4 loads (input L3-resident after harness restore; NT loads
// regressed +6us in an earlier round). Two independent loads per iteration.
// NEW: block 0 also zero-inits cnt[]/done[] (they live in poisoned workspace)
// with plain stores — the kernel boundary makes them visible to kernel 2,
// removing the need for a memset dispatch.
// ---------------------------------------------------------------------------
__global__ void __launch_bounds__(256) hist_partial_kernel(
        const int* __restrict__ idx,
        unsigned int* __restrict__ gpart,   // [HIST_BLOCKS][N_CODECS]
        unsigned int* __restrict__ cnt,     // [N_CODECS]  (zeroed here)
        unsigned int* __restrict__ done,    // [1]         (zeroed here)
        int n4) {
    __shared__ unsigned int lcounts[N_CODECS];
    #pragma unroll
    for (int i = threadIdx.x; i < N_CODECS; i += 256) lcounts[i] = 0u;

    if (blockIdx.x == 0) {
        #pragma unroll
        for (int i = threadIdx.x; i < N_CODECS; i += 256) cnt[i] = 0u;
        if (threadIdx.x == 0) done[0] = 0u;
    }
    __syncthreads();

    const int4* __restrict__ idx4 = (const int4*)idx;
    const int stride = gridDim.x * 256;     // 262144
    for (int i = blockIdx.x * 256 + threadIdx.x; i < n4; i += 2 * stride) {
        int4 a = idx4[i];
        int j = i + stride;
        bool has_b = (j < n4);
        int4 b = has_b ? idx4[j] : make_int4(0, 0, 0, 0);

        atomicAdd(&lcounts[a.x], 1u);   // LDS atomics only
        atomicAdd(&lcounts[a.y], 1u);
        atomicAdd(&lcounts[a.z], 1u);
        atomicAdd(&lcounts[a.w], 1u);
        if (has_b) {
            atomicAdd(&lcounts[b.x], 1u);
            atomicAdd(&lcounts[b.y], 1u);
            atomicAdd(&lcounts[b.z], 1u);
            atomicAdd(&lcounts[b.w], 1u);
        }
    }
    __syncthreads();

    // contention-free merge: plain coalesced stores to this block's slice
    unsigned int* __restrict__ mypart = gpart + (size_t)blockIdx.x * N_CODECS;
    #pragma unroll
    for (int i = 0; i < N_CODECS / 256; ++i) {
        int b = i * 256 + threadIdx.x;
        mypart[b] = lcounts[b];
    }
}

// ---------------------------------------------------------------------------
// Kernel 2: fused reduce + finalize (replaces the old reduce_kernel +
// finalize_kernel pair: one fewer launch slot, no p2 round-trip).
//   - 128 blocks x 512 threads. Block g column-sums its 8 partial rows
//     (wave reads 64 consecutive bins of one row = coalesced 256 B segment),
//     then atomicAdds its per-bin sums into cnt[1024] (128 adds per bin,
//     pipelined across 1024 distinct addresses -> ~1-2 us).
//   - Ticket pattern (proven in an earlier round): __syncthreads drains
//     vmcnt, thread 0 fences + takes a ticket; the LAST block re-reads cnt
//     via atomicAdd(p, 0) — an RMW at the coherence point, safe under
//     per-XCD L2 non-coherence — computes p*log(p+eps), block-reduces,
//     writes out = exp(-sum).
// ---------------------------------------------------------------------------
__global__ void __launch_bounds__(RED_THREADS) reduce_finalize_kernel(
        const unsigned int* __restrict__ gpart,   // [HIST_BLOCKS][N_CODECS]
        unsigned int* __restrict__ cnt,           // [N_CODECS]
        unsigned int* __restrict__ done,          // [1]
        float* __restrict__ out,
        float invN) {
    int t = threadIdx.x;

    const unsigned int* __restrict__ base =
        gpart + (size_t)(blockIdx.x * ROWS_PER_RED) * N_CODECS;
    unsigned int s0 = 0, s1 = 0;
    #pragma unroll
    for (int r = 0; r < ROWS_PER_RED; ++r) {
        s0 += base[(size_t)r * N_CODECS + t];
        s1 += base[(size_t)r * N_CODECS + t + RED_THREADS];
    }
    atomicAdd(&cnt[t], s0);
    atomicAdd(&cnt[t + RED_THREADS], s1);

    // __syncthreads drains vmcnt -> this block's atomics are globally
    // performed before thread 0 publishes the ticket.
    __syncthreads();

    __shared__ unsigned int ticket;
    if (t == 0) {
        __threadfence();                 // release
        ticket = atomicAdd(done, 1u);
    }
    __syncthreads();
    if (ticket != (unsigned int)(RED_BLOCKS - 1)) return;

    // ---- last block: finalize ----
    __threadfence();                     // acquire
    unsigned int c0 = atomicAdd(&cnt[t], 0u);                 // coherent read
    unsigned int c1 = atomicAdd(&cnt[t + RED_THREADS], 0u);
    float p0 = (float)c0 * invN;
    float p1 = (float)c1 * invN;
    float term = p0 * logf(p0 + EPS) + p1 * logf(p1 + EPS);

    #pragma unroll
    for (int off = 32; off > 0; off >>= 1) term += __shfl_down(term, off, 64);

    __shared__ float wsum[RED_THREADS / 64];
    int wave = t >> 6;
    int lane = t & 63;
    if (lane == 0) wsum[wave] = term;
    __syncthreads();

    if (t == 0) {
        float s = 0.0f;
        #pragma unroll
        for (int w = 0; w < RED_THREADS / 64; ++w) s += wsum[w];
        out[0] = expf(-s);
    }
}

extern "C" void kernel_launch(void* const* d_in, const int* in_sizes, int n_in,
                              void* d_out, int out_size, void* d_ws, size_t ws_size,
                              hipStream_t stream) {
    const int* indices = (const int*)d_in[0];
    int n = in_sizes[0];             // 16 * 1048576 = 16,777,216
    float* out = (float*)d_out;

    unsigned int* gpart = (unsigned int*)d_ws;                       // 4 MB
    unsigned int* cnt   = gpart + (size_t)HIST_BLOCKS * N_CODECS;    // 4 KB
    unsigned int* done  = cnt + N_CODECS;                            // 4 B

    int n4 = n >> 2;

    hist_partial_kernel<<<HIST_BLOCKS, 256, 0, stream>>>(indices, gpart, cnt, done, n4);
    reduce_finalize_kernel<<<RED_BLOCKS, RED_THREADS, 0, stream>>>(
        gpart, cnt, done, out, 1.0f / (float)n);
}